// Round 1
// baseline (204.973 us; speedup 1.0000x reference)
//
#include <hip/hip_runtime.h>
#include <math.h>

// x, x_r: (1, 3, 32, 512, 512) fp32. size=64 -> hc=wc=32, nh=nw=16.
// P[t,ph,pw] = mean over (c=3, 32x32) of |x - x_r|/2   (3072 elems/patch)
// out = log( mean_t( max(0, max_{ph,pw} P) ) )  -- scalar fp32.
//
// Round 9: occupancy for the read stream. rocprof: poison fills hit
//   6.84 TB/s (writes, 9% occ) while patch_sum reads at ~3.7 TB/s with a
//   grid-limited 16 waves/CU (1024 blk x 256 thr = 4 blk/CU). Reads need
//   in-flight bytes = BW * ~900cy nt-load latency; doubling resident waves
//   doubles MLP. Same structure: block b streams chunks 3b..3b+2 (chunk =
//   2048 vf4 = 16 rows x 512 cols of one (ch,t) frame; 96 KB contiguous
//   per input per block), 6 independent nt loads per inner iter into 3
//   scalar accumulators; now 512 thr x 4 iters instead of 256 x 8.
//   __launch_bounds__(512, 8) pins VGPR<=64 so 4 blocks (32 waves) fit/CU.
//   pw bin = (tid&127)>>3 still constant per thread (stride 512 = 0 mod 128).
// Kernel 2: one 1024-thread block: sum 6 chunk-contributions per patch,
//   per-t max, clamp, mean, log (unchanged, measured fast).

typedef float vf4 __attribute__((ext_vector_type(4)));

__global__ __launch_bounds__(512, 8) void patch_sum_kernel(
    const float* __restrict__ x, const float* __restrict__ xr,
    float* __restrict__ part) {
  const int b   = blockIdx.x;        // 0..1023
  const int tid = threadIdx.x;       // 0..511
  const size_t base4 = (size_t)b * 3 * 2048;
  const vf4* __restrict__ a4 = (const vf4*)x  + base4;
  const vf4* __restrict__ c4 = (const vf4*)xr + base4;

  float acc0 = 0.f, acc1 = 0.f, acc2 = 0.f;
#pragma unroll
  for (int i = 0; i < 4; ++i) {
    int o = i * 512 + tid;
    vf4 a0 = __builtin_nontemporal_load(&a4[o]);
    vf4 c0 = __builtin_nontemporal_load(&c4[o]);
    vf4 a1 = __builtin_nontemporal_load(&a4[2048 + o]);
    vf4 c1 = __builtin_nontemporal_load(&c4[2048 + o]);
    vf4 a2 = __builtin_nontemporal_load(&a4[4096 + o]);
    vf4 c2 = __builtin_nontemporal_load(&c4[4096 + o]);
    acc0 += fabsf(a0.x - c0.x) + fabsf(a0.y - c0.y)
          + fabsf(a0.z - c0.z) + fabsf(a0.w - c0.w);
    acc1 += fabsf(a1.x - c1.x) + fabsf(a1.y - c1.y)
          + fabsf(a1.z - c1.z) + fabsf(a1.w - c1.w);
    acc2 += fabsf(a2.x - c2.x) + fabsf(a2.y - c2.y)
          + fabsf(a2.z - c2.z) + fabsf(a2.w - c2.w);
  }

  // 8-lane group reduce for each chunk accumulator (bin = (tid&127)>>3).
#pragma unroll
  for (int o = 4; o > 0; o >>= 1) {
    acc0 += __shfl_down(acc0, o, 8);
    acc1 += __shfl_down(acc1, o, 8);
    acc2 += __shfl_down(acc2, o, 8);
  }
  __shared__ float s[3][64];
  if ((tid & 7) == 0) {
    int m = tid >> 3;                // 0..63 ; bin = m & 15
    s[0][m] = acc0;
    s[1][m] = acc1;
    s[2][m] = acc2;
  }
  __syncthreads();
  if (tid < 48) {
    int k = tid >> 4;                // which chunk of the 3
    int bin = tid & 15;              // pw
    part[(size_t)(b * 3 + k) * 16 + bin] =
        s[k][bin] + s[k][bin + 16] + s[k][bin + 32] + s[k][bin + 48];
  }
}

__global__ __launch_bounds__(1024) void finalize_kernel(
    const float* __restrict__ part, float* __restrict__ out) {
  const int tid = threadIdx.x;
  const int t = tid >> 5;             // 0..31
  const int j = tid & 31;
  float m = -1e30f;
#pragma unroll
  for (int k = 0; k < 8; ++k) {
    int p = t * 256 + j + 32 * k;     // patch id within frame t
    int ph = (p >> 4) & 15;
    int pw = p & 15;
    float v = 0.f;
#pragma unroll
    for (int ch = 0; ch < 3; ++ch) {
#pragma unroll
      for (int half = 0; half < 2; ++half) {
        int idx = ((ch << 10) + (t << 5) + (ph << 1) + half) * 16 + pw;
        v += part[idx];
      }
    }
    m = fmaxf(m, v);
  }
#pragma unroll
  for (int o = 16; o > 0; o >>= 1) m = fmaxf(m, __shfl_down(m, o, 32));
  __shared__ float s[32];
  if (j == 0) s[t] = fmaxf(m * (0.5f / 3072.0f), 0.f);  // scale + clamp at 0
  __syncthreads();
  if (tid < 32) {
    float v = s[tid];
#pragma unroll
    for (int o = 16; o > 0; o >>= 1) v += __shfl_down(v, o, 32);
    if (tid == 0) out[0] = logf(v * (1.0f / 32.0f));
  }
}

extern "C" void kernel_launch(void* const* d_in, const int* in_sizes, int n_in,
                              void* d_out, int out_size, void* d_ws, size_t ws_size,
                              hipStream_t stream) {
  const float* x  = (const float*)d_in[0];
  const float* xr = (const float*)d_in[1];
  float* part = (float*)d_ws;        // 3072*16 floats = 192 KB scratch
  float* out  = (float*)d_out;

  patch_sum_kernel<<<1024, 512, 0, stream>>>(x, xr, part);
  finalize_kernel<<<1, 1024, 0, stream>>>(part, out);
}